// Round 3
// baseline (960.751 us; speedup 1.0000x reference)
//
#include <hip/hip_runtime.h>

typedef unsigned short u16;
typedef __attribute__((ext_vector_type(8))) short short8;
typedef __attribute__((ext_vector_type(4))) float fx4;
typedef __attribute__((ext_vector_type(4))) int ix4;
typedef __attribute__((ext_vector_type(4))) unsigned short ux4;

__device__ __forceinline__ float bf2f(u16 h) {
  union { unsigned u; float f; } a; a.u = ((unsigned)h) << 16; return a.f;
}
__device__ __forceinline__ u16 f2bf(float f) {
  union { float f; unsigned u; } a; a.f = f;
  unsigned u = a.u;
  return (u16)((u + 0x7FFFu + ((u >> 16) & 1u)) >> 16);  // RNE
}

constexpr int S_LEN = 2048;
constexpr int DM = 2048;
constexpr int HD = 128;
constexpr int NH = 16;
constexpr float NEG = -1.0e9f;   // finite "-inf": exp underflows to 0

// ---------------------------------------------------------------------------
// GEMM: C[M,N] = A[M,K] @ W[N,K]^T + bias.  W and bias are fp32.
// MODE 0: A is bf16 (u16*), output fp32 row-major to o0 (out projection)
// MODE 1: A is fp32, QKV scatter (bf16): o0=Q [bh][s][d], o1=K, o2=V^T [bh][d][s]
// 128x128 tile, BK=32, 4 waves 2x2, each wave 4x4 16x16x32 MFMAs.
// ---------------------------------------------------------------------------
template<int M, int N, int K, int MODE>
__global__ __launch_bounds__(256)
void gemm_bt(const void* __restrict__ Av, const float* __restrict__ W,
             const float* __restrict__ bias,
             void* __restrict__ o0, u16* __restrict__ o1, u16* __restrict__ o2)
{
  constexpr int BK = 32;
  __shared__ u16 la[128 * BK];
  __shared__ u16 lb[128 * BK];
  const int tid  = threadIdx.x;
  const int lane = tid & 63;
  const int wv   = tid >> 6;
  const int wm   = wv >> 1, wn = wv & 1;
  const int quad = lane >> 4, l16 = lane & 15;
  const int m0 = blockIdx.y * 128, n0 = blockIdx.x * 128;

  fx4 acc[4][4] = {};

  for (int k0 = 0; k0 < K; k0 += BK) {
    __syncthreads();  // previous iter's LDS readers done
    if constexpr (MODE == 1) {
      const float* ap = (const float*)Av + (size_t)m0 * K;
      #pragma unroll
      for (int i = 0; i < 4; ++i) {
        int c = i * 256 + tid;               // 1024 chunks of 4 floats
        int row = c >> 3, col = (c & 7) * 4;
        fx4 v = *(const fx4*)&ap[(size_t)row * K + k0 + col];
        ux4 pk;
        pk[0] = f2bf(v[0]); pk[1] = f2bf(v[1]); pk[2] = f2bf(v[2]); pk[3] = f2bf(v[3]);
        *(ux4*)&la[row * BK + col] = pk;
      }
    } else {
      const u16* ap = (const u16*)Av + (size_t)m0 * K;
      #pragma unroll
      for (int i = 0; i < 2; ++i) {
        int c = i * 256 + tid;               // 512 chunks of 8 bf16
        int row = c >> 2, col = (c & 3) * 8;
        *(ix4*)&la[row * BK + col] = *(const ix4*)&ap[(size_t)row * K + k0 + col];
      }
    }
    {
      const float* wp = W + (size_t)n0 * K;
      #pragma unroll
      for (int i = 0; i < 4; ++i) {
        int c = i * 256 + tid;
        int row = c >> 3, col = (c & 7) * 4;
        fx4 v = *(const fx4*)&wp[(size_t)row * K + k0 + col];
        ux4 pk;
        pk[0] = f2bf(v[0]); pk[1] = f2bf(v[1]); pk[2] = f2bf(v[2]); pk[3] = f2bf(v[3]);
        *(ux4*)&lb[row * BK + col] = pk;
      }
    }
    __syncthreads();
    short8 af[4], bfg[4];
    #pragma unroll
    for (int t = 0; t < 4; ++t) {
      af[t]  = *(const short8*)&la[(wm * 64 + t * 16 + l16) * BK + quad * 8];
      bfg[t] = *(const short8*)&lb[(wn * 64 + t * 16 + l16) * BK + quad * 8];
    }
    #pragma unroll
    for (int mt = 0; mt < 4; ++mt)
      #pragma unroll
      for (int nt = 0; nt < 4; ++nt)
        acc[mt][nt] = __builtin_amdgcn_mfma_f32_16x16x32_bf16(af[mt], bfg[nt], acc[mt][nt], 0, 0, 0);
  }

  if constexpr (MODE == 0) {
    float* of = (float*)o0;
    #pragma unroll
    for (int nt = 0; nt < 4; ++nt) {
      int col = n0 + wn * 64 + nt * 16 + l16;
      float bz = bias[col];
      #pragma unroll
      for (int mt = 0; mt < 4; ++mt) {
        int row = m0 + wm * 64 + mt * 16 + quad * 4;
        #pragma unroll
        for (int r = 0; r < 4; ++r)
          of[(size_t)(row + r) * N + col] = acc[mt][nt][r] + bz;
      }
    }
  } else {
    // N=6144: block-col maps to exactly one of {q,k,v} and one head (128-wide)
    u16* q0 = (u16*)o0;
    const int which = n0 >> 11;
    const int head  = (n0 >> 7) & 15;
    const int b     = m0 >> 11;
    const int bh    = b * NH + head;
    #pragma unroll
    for (int nt = 0; nt < 4; ++nt) {
      int dcol = wn * 64 + nt * 16 + l16;           // 0..127 within head
      float bz = bias[n0 + dcol];
      #pragma unroll
      for (int mt = 0; mt < 4; ++mt) {
        int srow = (m0 & (S_LEN - 1)) + wm * 64 + mt * 16 + quad * 4;
        if (which == 2) {
          ux4 pk;
          #pragma unroll
          for (int r = 0; r < 4; ++r) pk[r] = f2bf(acc[mt][nt][r] + bz);
          *(ux4*)&o2[((size_t)bh * HD + dcol) * S_LEN + srow] = pk;  // V^T
        } else {
          u16* buf = (which == 0) ? q0 : o1;
          size_t base = ((size_t)bh * S_LEN + srow) * HD + dcol;
          #pragma unroll
          for (int r = 0; r < 4; ++r)
            buf[base + (size_t)r * HD] = f2bf(acc[mt][nt][r] + bz);
        }
      }
    }
  }
}

// ---------------------------------------------------------------------------
// RoPE in place on Q and K: layout [bh][s][128]; pairs (i, i+64), freq 10000^(-i/64)
// ---------------------------------------------------------------------------
__global__ __launch_bounds__(256)
void rope_kernel(u16* __restrict__ qbuf, u16* __restrict__ kbuf)
{
  int idx = blockIdx.x * 256 + threadIdx.x;   // 32*2048*64 total
  int i  = idx & 63;
  int s  = (idx >> 6) & (S_LEN - 1);
  int bh = idx >> 17;
  float invf = exp2f((float)i * -0.20762050594f);   // -log2(10000)/64
  float ang = (float)s * invf;
  float sn = sinf(ang), cs = cosf(ang);
  size_t base = ((size_t)bh * S_LEN + s) * HD + i;
  float q1 = bf2f(qbuf[base]), q2 = bf2f(qbuf[base + 64]);
  qbuf[base]      = f2bf(q1 * cs - q2 * sn);
  qbuf[base + 64] = f2bf(q2 * cs + q1 * sn);
  float k1 = bf2f(kbuf[base]), k2 = bf2f(kbuf[base + 64]);
  kbuf[base]      = f2bf(k1 * cs - k2 * sn);
  kbuf[base + 64] = f2bf(k2 * cs + k1 * sn);
}

// ---------------------------------------------------------------------------
// Flash attention (causal). Grid: (32 q-tiles, 32 bh). Block: 4 waves.
// Wave w owns 16 q-rows. Q frags in regs; K/V^T frags straight from global
// (L2-resident per bh); P converted C-layout -> A-layout via per-wave LDS.
// ---------------------------------------------------------------------------
__global__ __launch_bounds__(256)
void attn_kernel(const u16* __restrict__ qbuf, const u16* __restrict__ kbuf,
                 const u16* __restrict__ vtbuf, u16* __restrict__ ctx)
{
  __shared__ u16 lds_p[4][16 * 72];   // per-wave P tile, padded stride 72
  const int tid = threadIdx.x, lane = tid & 63, wv = tid >> 6;
  const int quad = lane >> 4, l16 = lane & 15;
  const int qt = 31 - blockIdx.x;     // long blocks first
  const int bh = blockIdx.y;
  const int head = bh & 15, b = bh >> 4;

  const size_t qrow0 = (size_t)bh * S_LEN + qt * 64 + wv * 16;
  short8 qf[4];
  #pragma unroll
  for (int kd = 0; kd < 4; ++kd)
    qf[kd] = *(const short8*)&qbuf[(qrow0 + l16) * HD + kd * 32 + quad * 8];

  fx4 o[8] = {};
  float mrow[4], lrow[4];
  #pragma unroll
  for (int r = 0; r < 4; ++r) { mrow[r] = NEG; lrow[r] = 0.f; }

  const float sc = 0.08838834764831845f;   // 1/sqrt(128)
  const int row_base = qt * 64 + wv * 16 + quad * 4;

  for (int kt = 0; kt <= qt; ++kt) {
    const int k0 = kt * 64;
    fx4 sacc[4] = {};
    #pragma unroll
    for (int snt = 0; snt < 4; ++snt) {
      const size_t krow = (size_t)bh * S_LEN + k0 + snt * 16 + l16;
      #pragma unroll
      for (int kd = 0; kd < 4; ++kd) {
        short8 kf = *(const short8*)&kbuf[krow * HD + kd * 32 + quad * 8];
        sacc[snt] = __builtin_amdgcn_mfma_f32_16x16x32_bf16(qf[kd], kf, sacc[snt], 0, 0, 0);
      }
    }
    float sv[4][4];
    #pragma unroll
    for (int snt = 0; snt < 4; ++snt)
      #pragma unroll
      for (int r = 0; r < 4; ++r) {
        float v = sacc[snt][r] * sc;
        if (kt == qt) {
          int col = k0 + snt * 16 + l16;
          if (col > row_base + r) v = NEG;
        }
        sv[snt][r] = v;
      }
    float mnew[4], alpha[4];
    #pragma unroll
    for (int r = 0; r < 4; ++r) {
      float mx = fmaxf(fmaxf(sv[0][r], sv[1][r]), fmaxf(sv[2][r], sv[3][r]));
      #pragma unroll
      for (int off = 1; off < 16; off <<= 1) mx = fmaxf(mx, __shfl_xor(mx, off, 64));
      mnew[r] = fmaxf(mrow[r], mx);
      alpha[r] = expf(mrow[r] - mnew[r]);
      mrow[r] = mnew[r];
    }
    #pragma unroll
    for (int r = 0; r < 4; ++r) {
      float rs = 0.f;
      #pragma unroll
      for (int snt = 0; snt < 4; ++snt) {
        float p = expf(sv[snt][r] - mnew[r]);
        sv[snt][r] = p;
        rs += p;
      }
      #pragma unroll
      for (int off = 1; off < 16; off <<= 1) rs += __shfl_xor(rs, off, 64);
      lrow[r] = lrow[r] * alpha[r] + rs;
    }
    // P: C-layout regs -> LDS [qrow][key] (bf16)
    #pragma unroll
    for (int snt = 0; snt < 4; ++snt)
      #pragma unroll
      for (int r = 0; r < 4; ++r)
        lds_p[wv][(quad * 4 + r) * 72 + snt * 16 + l16] = f2bf(sv[snt][r]);
    #pragma unroll
    for (int nd = 0; nd < 8; ++nd)
      #pragma unroll
      for (int r = 0; r < 4; ++r)
        o[nd][r] *= alpha[r];
    // PV: A=P from LDS (A-layout read), B=V^T from global (contiguous)
    #pragma unroll
    for (int kk = 0; kk < 2; ++kk) {
      short8 pf = *(const short8*)&lds_p[wv][l16 * 72 + kk * 32 + quad * 8];
      #pragma unroll
      for (int nd = 0; nd < 8; ++nd) {
        short8 vf = *(const short8*)&vtbuf[((size_t)bh * HD + nd * 16 + l16) * S_LEN + k0 + kk * 32 + quad * 8];
        o[nd] = __builtin_amdgcn_mfma_f32_16x16x32_bf16(pf, vf, o[nd], 0, 0, 0);
      }
    }
  }

  #pragma unroll
  for (int r = 0; r < 4; ++r) {
    float inv = 1.f / lrow[r];
    size_t m = (size_t)b * S_LEN + qt * 64 + wv * 16 + quad * 4 + r;
    #pragma unroll
    for (int nd = 0; nd < 8; ++nd)
      ctx[m * DM + head * HD + nd * 16 + l16] = f2bf(o[nd][r] * inv);
  }
}

// ---------------------------------------------------------------------------
extern "C" void kernel_launch(void* const* d_in, const int* in_sizes, int n_in,
                              void* d_out, int out_size, void* d_ws, size_t ws_size,
                              hipStream_t stream)
{
  const float* x    = (const float*)d_in[0];
  // d_in[1] = attn_mask (causal triu) — recomputed in-kernel, unused
  const float* Wqkv = (const float*)d_in[2];
  const float* bqkv = (const float*)d_in[3];
  const float* Wout = (const float*)d_in[4];
  const float* bout = (const float*)d_in[5];
  float* out = (float*)d_out;

  const size_t SEG = (size_t)8 * 1024 * 1024;   // 8M bf16 elems = 16MB per buffer
  u16* qbuf  = (u16*)d_ws;
  u16* kbuf  = qbuf + SEG;
  u16* vtbuf = kbuf + SEG;                      // ws total: 48MB
  u16* ctx   = (u16*)d_out;                     // bf16 ctx in 1st half of d_out
  float* tmpo = (float*)d_ws;                   // fp32 result over dead q/k bufs

  // 1) QKV projection + bias (fp32 in, bf16 out), scatter to Q/K/V^T
  gemm_bt<4096, 6144, 2048, 1><<<dim3(48, 32), 256, 0, stream>>>(
      x, Wqkv, bqkv, qbuf, kbuf, vtbuf);
  // 2) RoPE on Q, K
  rope_kernel<<<dim3(16384), 256, 0, stream>>>(qbuf, kbuf);
  // 3) causal flash attention -> ctx (bf16, in d_out)
  attn_kernel<<<dim3(32, 32), 256, 0, stream>>>(qbuf, kbuf, vtbuf, ctx);
  // 4) output projection + bias: reads ctx (d_out), writes fp32 into d_ws
  gemm_bt<4096, 2048, 2048, 0><<<dim3(16, 32), 256, 0, stream>>>(
      ctx, Wout, bout, tmpo, nullptr, nullptr);
  // 5) move fp32 result into d_out
  hipMemcpyAsync(out, tmpo, (size_t)out_size * sizeof(float),
                 hipMemcpyDeviceToDevice, stream);
}

// Round 5
// 954.530 us; speedup vs baseline: 1.0065x; 1.0065x over previous
//
#include <hip/hip_runtime.h>

typedef unsigned short u16;
typedef __attribute__((ext_vector_type(8))) short short8;
typedef __attribute__((ext_vector_type(4))) float fx4;
typedef __attribute__((ext_vector_type(4))) int ix4;
typedef __attribute__((ext_vector_type(4))) unsigned short ux4;

__device__ __forceinline__ float bf2f(u16 h) {
  union { unsigned u; float f; } a; a.u = ((unsigned)h) << 16; return a.f;
}
__device__ __forceinline__ u16 f2bf(float f) {
  union { float f; unsigned u; } a; a.f = f;
  unsigned u = a.u;
  return (u16)((u + 0x7FFFu + ((u >> 16) & 1u)) >> 16);  // RNE
}

// async global->LDS, 16B per lane. LDS dest must be wave-uniform base + lane*16.
__device__ __forceinline__ void gl_lds(const u16* g, u16* l) {
  __builtin_amdgcn_global_load_lds(
      (const __attribute__((address_space(1))) unsigned*)g,
      (__attribute__((address_space(3))) unsigned*)l, 16, 0, 0);
}

constexpr int S_LEN = 2048;
constexpr int DM = 2048;
constexpr int HD = 128;
constexpr int NH = 16;
constexpr float NEG = -1.0e9f;
constexpr float SC2 = 0.08838834764831845f * 1.4426950408889634f;  // 1/sqrt(128)*log2(e)

// ---------------------------------------------------------------------------
// fp32 -> bf16 bulk convert (memory-bound)
// ---------------------------------------------------------------------------
__global__ __launch_bounds__(256)
void cvt_kernel(const float* __restrict__ in, u16* __restrict__ out)
{
  int idx = blockIdx.x * 256 + threadIdx.x;
  fx4 v = *(const fx4*)&in[(size_t)idx * 4];
  ux4 pk;
  pk[0] = f2bf(v[0]); pk[1] = f2bf(v[1]); pk[2] = f2bf(v[2]); pk[3] = f2bf(v[3]);
  *(ux4*)&out[(size_t)idx * 4] = pk;
}

// ---------------------------------------------------------------------------
// GEMM: C[M,N] = A[M,K] @ W[N,K]^T + bias (bias fp32)
// MODE 0: fp32 out to o0;  MODE 1: QKV scatter bf16 (o0=Q, o1=K, o2=V^T)
// AB16/WB16: source dtype of A/W. bf16 sources use global_load_lds(16B) staging.
// LDS tiles are chunk-XOR-swizzled: LDS(row, cc) holds global(row, cc ^ ((row>>1)&3)).
// ---------------------------------------------------------------------------
template<int M, int N, int K, int MODE, bool AB16, bool WB16>
__global__ __launch_bounds__(256)
void gemm_bt(const void* __restrict__ Av, const void* __restrict__ Wv,
             const float* __restrict__ bias,
             void* __restrict__ o0, u16* __restrict__ o1, u16* __restrict__ o2)
{
  constexpr int BK = 32;
  __shared__ u16 la[128 * BK];
  __shared__ u16 lb[128 * BK];
  const int tid  = threadIdx.x;
  const int lane = tid & 63;
  const int wv   = tid >> 6;
  const int wm   = wv >> 1, wn = wv & 1;
  const int quad = lane >> 4, l16 = lane & 15;
  const int m0 = blockIdx.y * 128, n0 = blockIdx.x * 128;
  const int csw = (quad ^ ((l16 >> 1) & 3)) * 8;   // swizzled chunk for frag reads

  fx4 acc[4][4] = {};

  for (int k0 = 0; k0 < K; k0 += BK) {
    __syncthreads();
    if constexpr (AB16) {
      const u16* ap = (const u16*)Av + (size_t)m0 * K + k0;
      #pragma unroll
      for (int i = 0; i < 2; ++i) {
        int c = i * 256 + tid, row = c >> 2, cc = c & 3;
        int g = cc ^ ((row >> 1) & 3);
        gl_lds(ap + (size_t)row * K + g * 8, &la[c * 8]);
      }
    } else {
      const float* ap = (const float*)Av + (size_t)m0 * K + k0;
      #pragma unroll
      for (int i = 0; i < 2; ++i) {
        int c = i * 256 + tid, row = c >> 2, cc = c & 3;
        fx4 v0 = *(const fx4*)&ap[(size_t)row * K + cc * 8];
        fx4 v1 = *(const fx4*)&ap[(size_t)row * K + cc * 8 + 4];
        ux4 p0, p1;
        p0[0]=f2bf(v0[0]); p0[1]=f2bf(v0[1]); p0[2]=f2bf(v0[2]); p0[3]=f2bf(v0[3]);
        p1[0]=f2bf(v1[0]); p1[1]=f2bf(v1[1]); p1[2]=f2bf(v1[2]); p1[3]=f2bf(v1[3]);
        int s = cc ^ ((row >> 1) & 3);
        *(ux4*)&la[row * BK + s * 8]     = p0;
        *(ux4*)&la[row * BK + s * 8 + 4] = p1;
      }
    }
    if constexpr (WB16) {
      const u16* wp = (const u16*)Wv + (size_t)n0 * K + k0;
      #pragma unroll
      for (int i = 0; i < 2; ++i) {
        int c = i * 256 + tid, row = c >> 2, cc = c & 3;
        int g = cc ^ ((row >> 1) & 3);
        gl_lds(wp + (size_t)row * K + g * 8, &lb[c * 8]);
      }
    } else {
      const float* wp = (const float*)Wv + (size_t)n0 * K + k0;
      #pragma unroll
      for (int i = 0; i < 2; ++i) {
        int c = i * 256 + tid, row = c >> 2, cc = c & 3;
        fx4 v0 = *(const fx4*)&wp[(size_t)row * K + cc * 8];
        fx4 v1 = *(const fx4*)&wp[(size_t)row * K + cc * 8 + 4];
        ux4 p0, p1;
        p0[0]=f2bf(v0[0]); p0[1]=f2bf(v0[1]); p0[2]=f2bf(v0[2]); p0[3]=f2bf(v0[3]);
        p1[0]=f2bf(v1[0]); p1[1]=f2bf(v1[1]); p1[2]=f2bf(v1[2]); p1[3]=f2bf(v1[3]);
        int s = cc ^ ((row >> 1) & 3);
        *(ux4*)&lb[row * BK + s * 8]     = p0;
        *(ux4*)&lb[row * BK + s * 8 + 4] = p1;
      }
    }
    __syncthreads();
    short8 af[4], bfg[4];
    #pragma unroll
    for (int t = 0; t < 4; ++t) {
      af[t]  = *(const short8*)&la[(wm * 64 + t * 16 + l16) * BK + csw];
      bfg[t] = *(const short8*)&lb[(wn * 64 + t * 16 + l16) * BK + csw];
    }
    #pragma unroll
    for (int mt = 0; mt < 4; ++mt)
      #pragma unroll
      for (int nt = 0; nt < 4; ++nt)
        acc[mt][nt] = __builtin_amdgcn_mfma_f32_16x16x32_bf16(af[mt], bfg[nt], acc[mt][nt], 0, 0, 0);
  }

  if constexpr (MODE == 0) {
    float* of = (float*)o0;
    #pragma unroll
    for (int nt = 0; nt < 4; ++nt) {
      int col = n0 + wn * 64 + nt * 16 + l16;
      float bz = bias[col];
      #pragma unroll
      for (int mt = 0; mt < 4; ++mt) {
        int row = m0 + wm * 64 + mt * 16 + quad * 4;
        #pragma unroll
        for (int r = 0; r < 4; ++r)
          of[(size_t)(row + r) * N + col] = acc[mt][nt][r] + bz;
      }
    }
  } else {
    u16* q0 = (u16*)o0;
    const int which = n0 >> 11;
    const int head  = (n0 >> 7) & 15;
    const int b     = m0 >> 11;
    const int bh    = b * NH + head;
    #pragma unroll
    for (int nt = 0; nt < 4; ++nt) {
      int dcol = wn * 64 + nt * 16 + l16;
      float bz = bias[n0 + dcol];
      #pragma unroll
      for (int mt = 0; mt < 4; ++mt) {
        int srow = (m0 & (S_LEN - 1)) + wm * 64 + mt * 16 + quad * 4;
        if (which == 2) {
          ux4 pk;
          #pragma unroll
          for (int r = 0; r < 4; ++r) pk[r] = f2bf(acc[mt][nt][r] + bz);
          *(ux4*)&o2[((size_t)bh * HD + dcol) * S_LEN + srow] = pk;  // V^T
        } else {
          u16* buf = (which == 0) ? q0 : o1;
          size_t base = ((size_t)bh * S_LEN + srow) * HD + dcol;
          #pragma unroll
          for (int r = 0; r < 4; ++r)
            buf[base + (size_t)r * HD] = f2bf(acc[mt][nt][r] + bz);
        }
      }
    }
  }
}

// ---------------------------------------------------------------------------
// RoPE in place on Q and K
// ---------------------------------------------------------------------------
__global__ __launch_bounds__(256)
void rope_kernel(u16* __restrict__ qbuf, u16* __restrict__ kbuf)
{
  int idx = blockIdx.x * 256 + threadIdx.x;
  int i  = idx & 63;
  int s  = (idx >> 6) & (S_LEN - 1);
  int bh = idx >> 17;
  float invf = exp2f((float)i * -0.20762050594f);
  float ang = (float)s * invf;
  float sn = sinf(ang), cs = cosf(ang);
  size_t base = ((size_t)bh * S_LEN + s) * HD + i;
  float q1 = bf2f(qbuf[base]), q2 = bf2f(qbuf[base + 64]);
  qbuf[base]      = f2bf(q1 * cs - q2 * sn);
  qbuf[base + 64] = f2bf(q2 * cs + q1 * sn);
  float k1 = bf2f(kbuf[base]), k2 = bf2f(kbuf[base + 64]);
  kbuf[base]      = f2bf(k1 * cs - k2 * sn);
  kbuf[base + 64] = f2bf(k2 * cs + k1 * sn);
}

// ---------------------------------------------------------------------------
// Online-softmax tile step: scale, mask, row-max/sum (reduce over 16 lanes),
// rescale O, write P (bf16) to per-wave LDS in A-layout order.
// ---------------------------------------------------------------------------
__device__ __forceinline__ void soft_tile(fx4 s[4], float* m, float* l, fx4* o,
                                          u16* lp, bool mask, int rb, int k0,
                                          int l16, int quad)
{
  float sv[4][4];
  #pragma unroll
  for (int snt = 0; snt < 4; ++snt)
    #pragma unroll
    for (int r = 0; r < 4; ++r) {
      float v = s[snt][r] * SC2;
      if (mask && (k0 + snt * 16 + l16 > rb + r)) v = NEG;
      sv[snt][r] = v;
    }
  #pragma unroll
  for (int r = 0; r < 4; ++r) {
    float mx = fmaxf(fmaxf(sv[0][r], sv[1][r]), fmaxf(sv[2][r], sv[3][r]));
    #pragma unroll
    for (int off = 1; off < 16; off <<= 1) mx = fmaxf(mx, __shfl_xor(mx, off, 64));
    float mn = fmaxf(m[r], mx);
    float al = exp2f(m[r] - mn);
    m[r] = mn;
    float rs = 0.f;
    #pragma unroll
    for (int snt = 0; snt < 4; ++snt) {
      float pz = exp2f(sv[snt][r] - mn);
      sv[snt][r] = pz;
      rs += pz;
    }
    #pragma unroll
    for (int off = 1; off < 16; off <<= 1) rs += __shfl_xor(rs, off, 64);
    l[r] = l[r] * al + rs;
    #pragma unroll
    for (int nd = 0; nd < 8; ++nd) o[nd][r] *= al;
  }
  #pragma unroll
  for (int snt = 0; snt < 4; ++snt)
    #pragma unroll
    for (int r = 0; r < 4; ++r)
      lp[(quad * 4 + r) * 72 + snt * 16 + l16] = f2bf(sv[snt][r]);
}

// ---------------------------------------------------------------------------
// Flash attention (causal), paired q-tiles for load balance.
// Grid (16, 32): block p handles q-tiles qt_lo=p and qt_hi=31-p (64 rows each),
// uniform 33 MFMA-iterations per block. K/V^T tiles staged in LDS via
// global_load_lds with XOR-chunk swizzle, shared by all 4 waves and both
// q-tiles. K tile rows have 16 chunks (d=128), V^T rows have 8 chunks (key=64).
// ---------------------------------------------------------------------------
__global__ __launch_bounds__(256, 2)
void attn_kernel(const u16* __restrict__ qbuf, const u16* __restrict__ kbuf,
                 const u16* __restrict__ vtbuf, u16* __restrict__ ctx)
{
  __shared__ u16 lk[64 * 128];     // K tile  [key][d],  swizzled chunks
  __shared__ u16 lv[128 * 64];     // V^T tile [d][key], swizzled chunks
  __shared__ u16 lph[4][16 * 72];  // per-wave P (hi tile)
  __shared__ u16 lpl[4][16 * 72];  // per-wave P (lo tile)
  const int tid = threadIdx.x, lane = tid & 63, wv = tid >> 6;
  const int quad = lane >> 4, l16 = lane & 15;
  const int p = blockIdx.x, bh = blockIdx.y;
  const int qt_lo = p, qt_hi = 31 - p;
  const int head = bh & 15, b = bh >> 4;
  const int s8 = l16 & 7;          // frag-read swizzle index

  short8 qh[4], ql[4];
  {
    const size_t bh_ = ((size_t)bh * S_LEN + qt_hi * 64 + wv * 16 + l16) * HD;
    const size_t bl_ = ((size_t)bh * S_LEN + qt_lo * 64 + wv * 16 + l16) * HD;
    #pragma unroll
    for (int kd = 0; kd < 4; ++kd) {
      qh[kd] = *(const short8*)&qbuf[bh_ + kd * 32 + quad * 8];
      ql[kd] = *(const short8*)&qbuf[bl_ + kd * 32 + quad * 8];
    }
  }

  fx4 oh[8] = {}, ol[8] = {};
  float mh[4], lh[4], ml[4], ll[4];
  #pragma unroll
  for (int r = 0; r < 4; ++r) { mh[r] = NEG; lh[r] = 0.f; ml[r] = NEG; ll[r] = 0.f; }
  const int rb_hi = qt_hi * 64 + wv * 16 + quad * 4;
  const int rb_lo = qt_lo * 64 + wv * 16 + quad * 4;

  for (int kt = 0; kt <= qt_hi; ++kt) {
    const int k0 = kt * 64;
    const bool dlo = (kt <= qt_lo);
    __syncthreads();
    {
      const u16* kg = kbuf + ((size_t)bh * S_LEN + k0) * HD;
      const u16* vg = vtbuf + (size_t)bh * HD * S_LEN + k0;
      #pragma unroll
      for (int i = 0; i < 4; ++i) {           // K tile: 64 rows x 16 chunks
        int c = i * 256 + tid;
        int row = c >> 4, cc = c & 15;
        int g = cc ^ (row & 7);
        gl_lds(kg + (size_t)row * HD + g * 8, &lk[c * 8]);
      }
      #pragma unroll
      for (int i = 0; i < 4; ++i) {           // V^T tile: 128 rows x 8 chunks
        int c = i * 256 + tid;
        int row = c >> 3, cc = c & 7;
        int g = cc ^ (row & 7);
        gl_lds(vg + (size_t)row * S_LEN + g * 8, &lv[c * 8]);
      }
    }
    __syncthreads();

    fx4 sh[4] = {}, sl[4] = {};
    #pragma unroll
    for (int snt = 0; snt < 4; ++snt) {
      #pragma unroll
      for (int kd = 0; kd < 4; ++kd) {
        int cc = (kd * 4 + quad) ^ s8;
        short8 kf = *(const short8*)&lk[(snt * 16 + l16) * 128 + cc * 8];
        sh[snt] = __builtin_amdgcn_mfma_f32_16x16x32_bf16(qh[kd], kf, sh[snt], 0, 0, 0);
        if (dlo)
          sl[snt] = __builtin_amdgcn_mfma_f32_16x16x32_bf16(ql[kd], kf, sl[snt], 0, 0, 0);
      }
    }

    soft_tile(sh, mh, lh, oh, lph[wv], kt == qt_hi, rb_hi, k0, l16, quad);
    if (dlo) soft_tile(sl, ml, ll, ol, lpl[wv], kt == qt_lo, rb_lo, k0, l16, quad);

    #pragma unroll
    for (int kk = 0; kk < 2; ++kk) {
      short8 ph = *(const short8*)&lph[wv][l16 * 72 + kk * 32 + quad * 8];
      short8 pl = *(const short8*)&lpl[wv][l16 * 72 + kk * 32 + quad * 8];
      #pragma unroll
      for (int nd = 0; nd < 8; ++nd) {
        int cc = (kk * 4 + quad) ^ s8;
        short8 vf = *(const short8*)&lv[(nd * 16 + l16) * 64 + cc * 8];
        oh[nd] = __builtin_amdgcn_mfma_f32_16x16x32_bf16(ph, vf, oh[nd], 0, 0, 0);
        if (dlo)
          ol[nd] = __builtin_amdgcn_mfma_f32_16x16x32_bf16(pl, vf, ol[nd], 0, 0, 0);
      }
    }
  }

  #pragma unroll
  for (int r = 0; r < 4; ++r) {
    float ih = 1.f / lh[r], il = 1.f / ll[r];
    size_t mrh = (size_t)b * S_LEN + qt_hi * 64 + wv * 16 + quad * 4 + r;
    size_t mrl = (size_t)b * S_LEN + qt_lo * 64 + wv * 16 + quad * 4 + r;
    #pragma unroll
    for (int nd = 0; nd < 8; ++nd) {
      ctx[mrh * DM + head * HD + nd * 16 + l16] = f2bf(oh[nd][r] * ih);
      ctx[mrl * DM + head * HD + nd * 16 + l16] = f2bf(ol[nd][r] * il);
    }
  }
}

// ---------------------------------------------------------------------------
extern "C" void kernel_launch(void* const* d_in, const int* in_sizes, int n_in,
                              void* d_out, int out_size, void* d_ws, size_t ws_size,
                              hipStream_t stream)
{
  const float* x    = (const float*)d_in[0];
  const float* Wqkv = (const float*)d_in[2];
  const float* bqkv = (const float*)d_in[3];
  const float* Wout = (const float*)d_in[4];
  const float* bout = (const float*)d_in[5];
  float* out = (float*)d_out;
  u16* ctx = (u16*)d_out;   // bf16 ctx in first half of d_out

  constexpr size_t XB_E = (size_t)4096 * 2048;   // 8.39M elems
  constexpr size_t WQ_E = (size_t)6144 * 2048;
  constexpr size_t WO_E = (size_t)2048 * 2048;
  constexpr size_t NEED = (XB_E + WQ_E + WO_E + 3 * XB_E) * 2;  // ~101 MB

  if (ws_size >= NEED) {
    u16* xb  = (u16*)d_ws;
    u16* wqb = xb + XB_E;
    u16* wob = wqb + WQ_E;
    u16* qb  = wob + WO_E;
    u16* kb  = qb + XB_E;
    u16* vb  = kb + XB_E;
    float* tmpo = (float*)d_ws;   // 33.5 MB over xb+wqb (41.9 MB, dead at out-proj)

    cvt_kernel<<<dim3(XB_E / 1024), 256, 0, stream>>>(x, xb);
    cvt_kernel<<<dim3(WQ_E / 1024), 256, 0, stream>>>(Wqkv, wqb);
    cvt_kernel<<<dim3(WO_E / 1024), 256, 0, stream>>>(Wout, wob);
    gemm_bt<4096, 6144, 2048, 1, true, true><<<dim3(48, 32), 256, 0, stream>>>(
        xb, wqb, bqkv, qb, kb, vb);
    rope_kernel<<<dim3(16384), 256, 0, stream>>>(qb, kb);
    attn_kernel<<<dim3(16, 32), 256, 0, stream>>>(qb, kb, vb, ctx);
    gemm_bt<4096, 2048, 2048, 0, true, true><<<dim3(16, 32), 256, 0, stream>>>(
        ctx, wob, bout, tmpo, nullptr, nullptr);
    hipMemcpyAsync(out, tmpo, (size_t)out_size * sizeof(float),
                   hipMemcpyDeviceToDevice, stream);
  } else {
    // fallback: 48 MiB ws, fused fp32->bf16 staging in GEMMs
    u16* qb = (u16*)d_ws;
    u16* kb = qb + XB_E;
    u16* vb = kb + XB_E;
    float* tmpo = (float*)d_ws;   // over dead qb/kb at out-proj time

    gemm_bt<4096, 6144, 2048, 1, false, false><<<dim3(48, 32), 256, 0, stream>>>(
        x, Wqkv, bqkv, qb, kb, vb);
    rope_kernel<<<dim3(16384), 256, 0, stream>>>(qb, kb);
    attn_kernel<<<dim3(16, 32), 256, 0, stream>>>(qb, kb, vb, ctx);
    gemm_bt<4096, 2048, 2048, 0, true, false><<<dim3(16, 32), 256, 0, stream>>>(
        ctx, Wout, bout, tmpo, nullptr, nullptr);
    hipMemcpyAsync(out, tmpo, (size_t)out_size * sizeof(float),
                   hipMemcpyDeviceToDevice, stream);
  }
}

// Round 6
// 530.706 us; speedup vs baseline: 1.8103x; 1.7986x over previous
//
#include <hip/hip_runtime.h>

typedef unsigned short u16;
typedef __attribute__((ext_vector_type(8))) short short8;
typedef __attribute__((ext_vector_type(4))) float fx4;
typedef __attribute__((ext_vector_type(4))) int ix4;
typedef __attribute__((ext_vector_type(4))) unsigned short ux4;

__device__ __forceinline__ float bf2f(u16 h) {
  union { unsigned u; float f; } a; a.u = ((unsigned)h) << 16; return a.f;
}
__device__ __forceinline__ u16 f2bf(float f) {
  union { float f; unsigned u; } a; a.f = f;
  unsigned u = a.u;
  return (u16)((u + 0x7FFFu + ((u >> 16) & 1u)) >> 16);  // RNE
}

// async global->LDS, 16B per lane. LDS dest must be wave-uniform base + lane*16.
__device__ __forceinline__ void gl_lds(const u16* g, u16* l) {
  __builtin_amdgcn_global_load_lds(
      (const __attribute__((address_space(1))) unsigned*)g,
      (__attribute__((address_space(3))) unsigned*)l, 16, 0, 0);
}

constexpr int S_LEN = 2048;
constexpr int DM = 2048;
constexpr int HD = 128;
constexpr int NH = 16;
constexpr float NEG = -1.0e9f;
constexpr float SC2 = 0.08838834764831845f * 1.4426950408889634f;  // 1/sqrt(128)*log2(e)

// ---------------------------------------------------------------------------
// fp32 -> bf16 bulk convert (memory-bound)
// ---------------------------------------------------------------------------
__global__ __launch_bounds__(256)
void cvt_kernel(const float* __restrict__ in, u16* __restrict__ out)
{
  int idx = blockIdx.x * 256 + threadIdx.x;
  fx4 v = *(const fx4*)&in[(size_t)idx * 4];
  ux4 pk;
  pk[0] = f2bf(v[0]); pk[1] = f2bf(v[1]); pk[2] = f2bf(v[2]); pk[3] = f2bf(v[3]);
  *(ux4*)&out[(size_t)idx * 4] = pk;
}

// ---------------------------------------------------------------------------
// GEMM: C[M,N] = A[M,K] @ W[N,K]^T + bias (bias fp32)
// MODE 0: fp32 out to o0;  MODE 1: QKV scatter bf16 (o0=Q, o1=K, o2=V^T)
// AB16/WB16: source dtype of A/W. bf16 sources use global_load_lds(16B) staging.
// LDS tiles are chunk-XOR-swizzled: LDS(row, cc) holds global(row, cc ^ ((row>>1)&3)).
// ---------------------------------------------------------------------------
template<int M, int N, int K, int MODE, bool AB16, bool WB16>
__global__ __launch_bounds__(256)
void gemm_bt(const void* __restrict__ Av, const void* __restrict__ Wv,
             const float* __restrict__ bias,
             void* __restrict__ o0, u16* __restrict__ o1, u16* __restrict__ o2)
{
  constexpr int BK = 32;
  __shared__ u16 la[128 * BK];
  __shared__ u16 lb[128 * BK];
  const int tid  = threadIdx.x;
  const int lane = tid & 63;
  const int wv   = tid >> 6;
  const int wm   = wv >> 1, wn = wv & 1;
  const int quad = lane >> 4, l16 = lane & 15;
  const int m0 = blockIdx.y * 128, n0 = blockIdx.x * 128;
  const int csw = (quad ^ ((l16 >> 1) & 3)) * 8;   // swizzled chunk for frag reads

  fx4 acc[4][4] = {};

  for (int k0 = 0; k0 < K; k0 += BK) {
    __syncthreads();
    if constexpr (AB16) {
      const u16* ap = (const u16*)Av + (size_t)m0 * K + k0;
      #pragma unroll
      for (int i = 0; i < 2; ++i) {
        int c = i * 256 + tid, row = c >> 2, cc = c & 3;
        int g = cc ^ ((row >> 1) & 3);
        gl_lds(ap + (size_t)row * K + g * 8, &la[c * 8]);
      }
    } else {
      const float* ap = (const float*)Av + (size_t)m0 * K + k0;
      #pragma unroll
      for (int i = 0; i < 2; ++i) {
        int c = i * 256 + tid, row = c >> 2, cc = c & 3;
        fx4 v0 = *(const fx4*)&ap[(size_t)row * K + cc * 8];
        fx4 v1 = *(const fx4*)&ap[(size_t)row * K + cc * 8 + 4];
        ux4 p0, p1;
        p0[0]=f2bf(v0[0]); p0[1]=f2bf(v0[1]); p0[2]=f2bf(v0[2]); p0[3]=f2bf(v0[3]);
        p1[0]=f2bf(v1[0]); p1[1]=f2bf(v1[1]); p1[2]=f2bf(v1[2]); p1[3]=f2bf(v1[3]);
        int s = cc ^ ((row >> 1) & 3);
        *(ux4*)&la[row * BK + s * 8]     = p0;
        *(ux4*)&la[row * BK + s * 8 + 4] = p1;
      }
    }
    if constexpr (WB16) {
      const u16* wp = (const u16*)Wv + (size_t)n0 * K + k0;
      #pragma unroll
      for (int i = 0; i < 2; ++i) {
        int c = i * 256 + tid, row = c >> 2, cc = c & 3;
        int g = cc ^ ((row >> 1) & 3);
        gl_lds(wp + (size_t)row * K + g * 8, &lb[c * 8]);
      }
    } else {
      const float* wp = (const float*)Wv + (size_t)n0 * K + k0;
      #pragma unroll
      for (int i = 0; i < 2; ++i) {
        int c = i * 256 + tid, row = c >> 2, cc = c & 3;
        fx4 v0 = *(const fx4*)&wp[(size_t)row * K + cc * 8];
        fx4 v1 = *(const fx4*)&wp[(size_t)row * K + cc * 8 + 4];
        ux4 p0, p1;
        p0[0]=f2bf(v0[0]); p0[1]=f2bf(v0[1]); p0[2]=f2bf(v0[2]); p0[3]=f2bf(v0[3]);
        p1[0]=f2bf(v1[0]); p1[1]=f2bf(v1[1]); p1[2]=f2bf(v1[2]); p1[3]=f2bf(v1[3]);
        int s = cc ^ ((row >> 1) & 3);
        *(ux4*)&lb[row * BK + s * 8]     = p0;
        *(ux4*)&lb[row * BK + s * 8 + 4] = p1;
      }
    }
    __syncthreads();
    short8 af[4], bfg[4];
    #pragma unroll
    for (int t = 0; t < 4; ++t) {
      af[t]  = *(const short8*)&la[(wm * 64 + t * 16 + l16) * BK + csw];
      bfg[t] = *(const short8*)&lb[(wn * 64 + t * 16 + l16) * BK + csw];
    }
    #pragma unroll
    for (int mt = 0; mt < 4; ++mt)
      #pragma unroll
      for (int nt = 0; nt < 4; ++nt)
        acc[mt][nt] = __builtin_amdgcn_mfma_f32_16x16x32_bf16(af[mt], bfg[nt], acc[mt][nt], 0, 0, 0);
  }

  if constexpr (MODE == 0) {
    float* of = (float*)o0;
    #pragma unroll
    for (int nt = 0; nt < 4; ++nt) {
      int col = n0 + wn * 64 + nt * 16 + l16;
      float bz = bias[col];
      #pragma unroll
      for (int mt = 0; mt < 4; ++mt) {
        int row = m0 + wm * 64 + mt * 16 + quad * 4;
        #pragma unroll
        for (int r = 0; r < 4; ++r)
          of[(size_t)(row + r) * N + col] = acc[mt][nt][r] + bz;
      }
    }
  } else {
    u16* q0 = (u16*)o0;
    const int which = n0 >> 11;
    const int head  = (n0 >> 7) & 15;
    const int b     = m0 >> 11;
    const int bh    = b * NH + head;
    #pragma unroll
    for (int nt = 0; nt < 4; ++nt) {
      int dcol = wn * 64 + nt * 16 + l16;
      float bz = bias[n0 + dcol];
      #pragma unroll
      for (int mt = 0; mt < 4; ++mt) {
        int srow = (m0 & (S_LEN - 1)) + wm * 64 + mt * 16 + quad * 4;
        if (which == 2) {
          ux4 pk;
          #pragma unroll
          for (int r = 0; r < 4; ++r) pk[r] = f2bf(acc[mt][nt][r] + bz);
          *(ux4*)&o2[((size_t)bh * HD + dcol) * S_LEN + srow] = pk;  // V^T
        } else {
          u16* buf = (which == 0) ? q0 : o1;
          size_t base = ((size_t)bh * S_LEN + srow) * HD + dcol;
          #pragma unroll
          for (int r = 0; r < 4; ++r)
            buf[base + (size_t)r * HD] = f2bf(acc[mt][nt][r] + bz);
        }
      }
    }
  }
}

// ---------------------------------------------------------------------------
// RoPE in place on Q and K
// ---------------------------------------------------------------------------
__global__ __launch_bounds__(256)
void rope_kernel(u16* __restrict__ qbuf, u16* __restrict__ kbuf)
{
  int idx = blockIdx.x * 256 + threadIdx.x;
  int i  = idx & 63;
  int s  = (idx >> 6) & (S_LEN - 1);
  int bh = idx >> 17;
  float invf = exp2f((float)i * -0.20762050594f);
  float ang = (float)s * invf;
  float sn = sinf(ang), cs = cosf(ang);
  size_t base = ((size_t)bh * S_LEN + s) * HD + i;
  float q1 = bf2f(qbuf[base]), q2 = bf2f(qbuf[base + 64]);
  qbuf[base]      = f2bf(q1 * cs - q2 * sn);
  qbuf[base + 64] = f2bf(q2 * cs + q1 * sn);
  float k1 = bf2f(kbuf[base]), k2 = bf2f(kbuf[base + 64]);
  kbuf[base]      = f2bf(k1 * cs - k2 * sn);
  kbuf[base + 64] = f2bf(k2 * cs + k1 * sn);
}

// ---------------------------------------------------------------------------
// Flash attention (causal). Grid (32 qt, 32 bh), 4 waves/block, one 64-row
// q-tile per block (fits in 128 VGPRs — round-5's paired-tile variant spilled
// ~2.4 GB to scratch). K/V^T staged in LDS via global_load_lds with XOR-chunk
// swizzle, shared by all 4 waves. K tile rows: 16 chunks (d=128); V^T rows:
// 8 chunks (key=64).
// ---------------------------------------------------------------------------
__global__ __launch_bounds__(256, 2)
void attn_kernel(const u16* __restrict__ qbuf, const u16* __restrict__ kbuf,
                 const u16* __restrict__ vtbuf, u16* __restrict__ ctx)
{
  __shared__ u16 lk[64 * 128];     // K tile  [key][d],  swizzled chunks
  __shared__ u16 lv[128 * 64];     // V^T tile [d][key], swizzled chunks
  __shared__ u16 lp[4][16 * 72];   // per-wave P tile (A-layout round-trip)
  const int tid = threadIdx.x, lane = tid & 63, wv = tid >> 6;
  const int quad = lane >> 4, l16 = lane & 15;
  const int qt = 31 - blockIdx.x;  // longest q-tiles dispatched first
  const int bh = blockIdx.y;
  const int head = bh & 15, b = bh >> 4;
  const int s8 = l16 & 7;          // frag-read swizzle index

  short8 qf[4];
  {
    const size_t q_ = ((size_t)bh * S_LEN + qt * 64 + wv * 16 + l16) * HD;
    #pragma unroll
    for (int kd = 0; kd < 4; ++kd)
      qf[kd] = *(const short8*)&qbuf[q_ + kd * 32 + quad * 8];
  }

  fx4 o[8] = {};
  float m[4], l[4];
  #pragma unroll
  for (int r = 0; r < 4; ++r) { m[r] = NEG; l[r] = 0.f; }
  const int rb = qt * 64 + wv * 16 + quad * 4;

  for (int kt = 0; kt <= qt; ++kt) {
    const int k0 = kt * 64;
    __syncthreads();
    {
      const u16* kg = kbuf + ((size_t)bh * S_LEN + k0) * HD;
      const u16* vg = vtbuf + (size_t)bh * HD * S_LEN + k0;
      #pragma unroll
      for (int i = 0; i < 4; ++i) {           // K tile: 64 rows x 16 chunks
        int c = i * 256 + tid;
        int row = c >> 4, cc = c & 15;
        int g = cc ^ (row & 7);
        gl_lds(kg + (size_t)row * HD + g * 8, &lk[c * 8]);
      }
      #pragma unroll
      for (int i = 0; i < 4; ++i) {           // V^T tile: 128 rows x 8 chunks
        int c = i * 256 + tid;
        int row = c >> 3, cc = c & 7;
        int g = cc ^ (row & 7);
        gl_lds(vg + (size_t)row * S_LEN + g * 8, &lv[c * 8]);
      }
    }
    __syncthreads();

    // QK^T
    fx4 sacc[4] = {};
    #pragma unroll
    for (int snt = 0; snt < 4; ++snt) {
      #pragma unroll
      for (int kd = 0; kd < 4; ++kd) {
        int cc = (kd * 4 + quad) ^ s8;
        short8 kf = *(const short8*)&lk[(snt * 16 + l16) * 128 + cc * 8];
        sacc[snt] = __builtin_amdgcn_mfma_f32_16x16x32_bf16(qf[kd], kf, sacc[snt], 0, 0, 0);
      }
    }

    // online softmax (exp2 domain), write P to per-wave LDS in A-layout order
    float sv[4][4];
    #pragma unroll
    for (int snt = 0; snt < 4; ++snt)
      #pragma unroll
      for (int r = 0; r < 4; ++r) {
        float v = sacc[snt][r] * SC2;
        if (kt == qt && (k0 + snt * 16 + l16 > rb + r)) v = NEG;
        sv[snt][r] = v;
      }
    #pragma unroll
    for (int r = 0; r < 4; ++r) {
      float mx = fmaxf(fmaxf(sv[0][r], sv[1][r]), fmaxf(sv[2][r], sv[3][r]));
      #pragma unroll
      for (int off = 1; off < 16; off <<= 1) mx = fmaxf(mx, __shfl_xor(mx, off, 64));
      float mn = fmaxf(m[r], mx);
      float al = exp2f(m[r] - mn);
      m[r] = mn;
      float rs = 0.f;
      #pragma unroll
      for (int snt = 0; snt < 4; ++snt) {
        float pz = exp2f(sv[snt][r] - mn);
        sv[snt][r] = pz;
        rs += pz;
      }
      #pragma unroll
      for (int off = 1; off < 16; off <<= 1) rs += __shfl_xor(rs, off, 64);
      l[r] = l[r] * al + rs;
      #pragma unroll
      for (int nd = 0; nd < 8; ++nd) o[nd][r] *= al;
    }
    #pragma unroll
    for (int snt = 0; snt < 4; ++snt)
      #pragma unroll
      for (int r = 0; r < 4; ++r)
        lp[wv][(quad * 4 + r) * 72 + snt * 16 + l16] = f2bf(sv[snt][r]);

    // PV: A=P from LDS, B=V^T frags from LDS
    #pragma unroll
    for (int kk = 0; kk < 2; ++kk) {
      short8 pf = *(const short8*)&lp[wv][l16 * 72 + kk * 32 + quad * 8];
      #pragma unroll
      for (int nd = 0; nd < 8; ++nd) {
        int cc = (kk * 4 + quad) ^ s8;
        short8 vf = *(const short8*)&lv[(nd * 16 + l16) * 64 + cc * 8];
        o[nd] = __builtin_amdgcn_mfma_f32_16x16x32_bf16(pf, vf, o[nd], 0, 0, 0);
      }
    }
  }

  #pragma unroll
  for (int r = 0; r < 4; ++r) {
    float inv = 1.f / l[r];
    size_t mr = (size_t)b * S_LEN + qt * 64 + wv * 16 + quad * 4 + r;
    #pragma unroll
    for (int nd = 0; nd < 8; ++nd)
      ctx[mr * DM + head * HD + nd * 16 + l16] = f2bf(o[nd][r] * inv);
  }
}

// ---------------------------------------------------------------------------
extern "C" void kernel_launch(void* const* d_in, const int* in_sizes, int n_in,
                              void* d_out, int out_size, void* d_ws, size_t ws_size,
                              hipStream_t stream)
{
  const float* x    = (const float*)d_in[0];
  const float* Wqkv = (const float*)d_in[2];
  const float* bqkv = (const float*)d_in[3];
  const float* Wout = (const float*)d_in[4];
  const float* bout = (const float*)d_in[5];
  float* out = (float*)d_out;
  u16* ctx = (u16*)d_out;   // bf16 ctx in first half of d_out

  constexpr size_t XB_E = (size_t)4096 * 2048;   // 8.39M elems
  constexpr size_t WQ_E = (size_t)6144 * 2048;
  constexpr size_t WO_E = (size_t)2048 * 2048;
  constexpr size_t NEED = (XB_E + WQ_E + WO_E + 3 * XB_E) * 2;  // ~101 MB

  if (ws_size >= NEED) {
    u16* xb  = (u16*)d_ws;
    u16* wqb = xb + XB_E;
    u16* wob = wqb + WQ_E;
    u16* qb  = wob + WO_E;
    u16* kb  = qb + XB_E;
    u16* vb  = kb + XB_E;
    float* tmpo = (float*)d_ws;   // 33.5 MB over xb+wqb (dead at out-proj)

    cvt_kernel<<<dim3(XB_E / 1024), 256, 0, stream>>>(x, xb);
    cvt_kernel<<<dim3(WQ_E / 1024), 256, 0, stream>>>(Wqkv, wqb);
    cvt_kernel<<<dim3(WO_E / 1024), 256, 0, stream>>>(Wout, wob);
    gemm_bt<4096, 6144, 2048, 1, true, true><<<dim3(48, 32), 256, 0, stream>>>(
        xb, wqb, bqkv, qb, kb, vb);
    rope_kernel<<<dim3(16384), 256, 0, stream>>>(qb, kb);
    attn_kernel<<<dim3(32, 32), 256, 0, stream>>>(qb, kb, vb, ctx);
    gemm_bt<4096, 2048, 2048, 0, true, true><<<dim3(16, 32), 256, 0, stream>>>(
        ctx, wob, bout, tmpo, nullptr, nullptr);
    hipMemcpyAsync(out, tmpo, (size_t)out_size * sizeof(float),
                   hipMemcpyDeviceToDevice, stream);
  } else {
    // fallback: 48 MiB ws, fused fp32->bf16 staging in GEMMs
    u16* qb = (u16*)d_ws;
    u16* kb = qb + XB_E;
    u16* vb = kb + XB_E;
    float* tmpo = (float*)d_ws;   // over dead qb/kb at out-proj time

    gemm_bt<4096, 6144, 2048, 1, false, false><<<dim3(48, 32), 256, 0, stream>>>(
        x, Wqkv, bqkv, qb, kb, vb);
    rope_kernel<<<dim3(16384), 256, 0, stream>>>(qb, kb);
    attn_kernel<<<dim3(32, 32), 256, 0, stream>>>(qb, kb, vb, ctx);
    gemm_bt<4096, 2048, 2048, 0, true, false><<<dim3(16, 32), 256, 0, stream>>>(
        ctx, Wout, bout, tmpo, nullptr, nullptr);
    hipMemcpyAsync(out, tmpo, (size_t)out_size * sizeof(float),
                   hipMemcpyDeviceToDevice, stream);
  }
}